// Round 13
// baseline (260.382 us; speedup 1.0000x reference)
//
#include <hip/hip_runtime.h>

typedef __attribute__((ext_vector_type(8))) _Float16 f16x8;
typedef __attribute__((ext_vector_type(4))) _Float16 f16x4;
typedef __attribute__((ext_vector_type(2))) _Float16 f16x2;
typedef __attribute__((ext_vector_type(4))) float f32x4;
typedef __attribute__((ext_vector_type(2))) float f32x2;

#define T_STEPS 49
#define BM 8                 // batch rows per WG (half-filled MFMA M-dim)
#define OUTSTRIDE (4096*64)
#define YSTR 132   // f16/row: 264B = 66 dw == 2 mod 8 (write-conflict-free, measured 0)
#define HSTR 260   // f16/row: 520B = 130 dw == 2 mod 8

__device__ __forceinline__ f16x8 ld_frag(const _Float16* p) {
  f16x4 a = *(const f16x4*)p;        // rows 8B-aligned
  f16x4 b = *(const f16x4*)(p + 4);
  return __builtin_shufflevector(a, b, 0,1,2,3,4,5,6,7);
}
// Backend bug workaround: v-op with two SGPR sources violates constant-bus rule.
__device__ __forceinline__ float vsub(float a, float b) {
  float r;
  asm("v_sub_f32 %0, %1, %2" : "=v"(r) : "v"(a), "v"(b));
  return r;
}
// Packed f32 via native vector ops (compiler-encoded VOP3P; R10/R11: never
// hand-write VOP3P asm — modifier defaults corrupt the hi half).
__device__ __forceinline__ f32x2 vfma2(f32x2 a, f32x2 b, f32x2 c) {
  return __builtin_elementwise_fma(a, b, c);
}
__device__ __forceinline__ f32x2 tanh2(f32x2 x) {
  const f32x2 c2  = { 2.885390081777927f, 2.885390081777927f };
  const f32x2 one = { 1.f, 1.f };
  const f32x2 m2  = { -2.f, -2.f };
  f32x2 t = x * c2;
  f32x2 e;
  e[0] = __builtin_amdgcn_exp2f(t[0]);
  e[1] = __builtin_amdgcn_exp2f(t[1]);
  f32x2 ep1 = e + one;
  f32x2 r;
  r[0] = __builtin_amdgcn_rcpf(ep1[0]);
  r[1] = __builtin_amdgcn_rcpf(ep1[1]);
  return vfma2(r, m2, one);           // 1 - 2/(e^{2x}+1)
}
__device__ __forceinline__ f16x4 cvt4(f32x2 a, f32x2 b) {
  f16x2 h0 = __builtin_bit_cast(f16x2, __builtin_amdgcn_cvt_pkrtz(a[0], a[1]));
  f16x2 h1 = __builtin_bit_cast(f16x2, __builtin_amdgcn_cvt_pkrtz(b[0], b[1]));
  return __builtin_shufflevector(h0, h1, 0,1,2,3);
}

// BM=8, 512-thread WG, grid 512 = 2 WGs/CU: two INDEPENDENT barrier groups per
// CU dephase so one group's barrier drain overlaps the other's compute (the
// kernel is latency-bound: R12 wall 1838 cyc/eval vs busiest pipe 620).
// Cost: 16x16 MFMAs half-filled in M (lanes m>=8 carry a dummy zero-state;
// matmul rows are independent so garbage never crosses rows). Otherwise R12.
__global__ __launch_bounds__(512, 4)
void node_rk4_kernel(const float* __restrict__ x0, const float* __restrict__ tarr,
                     const float* __restrict__ W1, const float* __restrict__ b1,
                     const float* __restrict__ W2, const float* __restrict__ b2,
                     float* __restrict__ out)
{
  __shared__ __align__(16) _Float16 Yh[16][YSTR];
  __shared__ __align__(16) _Float16 Hh[16][HSTR];

  const int tid  = threadIdx.x;
  const int w    = tid >> 6;        // wave 0..7
  const int lane = tid & 63;
  const int m    = lane & 15;       // MFMA row slot; batch row valid iff m<8
  const int g    = lane >> 4;       // 0..3
  const int row0 = (int)blockIdx.x * BM;
  const bool rowok = (m < BM);

  // ---- weight fragments in registers (identical packing to R12) ----
  f16x8 wB1[2][4], wB2[8];
#pragma unroll
  for (int c = 0; c < 2; ++c)
#pragma unroll
    for (int kk = 0; kk < 4; ++kk) {
      f16x8 v;
#pragma unroll
      for (int j = 0; j < 8; ++j)
        v[j] = (_Float16)W1[(kk*32 + 8*g + j)*256 + (32*w + 16*c + m)];
      wB1[c][kk] = v;
    }
#pragma unroll
  for (int kk = 0; kk < 8; ++kk) {
    f16x8 v;
#pragma unroll
    for (int j = 0; j < 8; ++j)
      v[j] = (_Float16)W2[(kk*32 + 8*g + j)*128 + (16*w + m)];
    wB2[kk] = v;
  }
  // biases: transposed D-frag -> per-reg bias (row index 4g+i of the tile)
  f32x4 bb1[2], bb2v;
#pragma unroll
  for (int c = 0; c < 2; ++c)
#pragma unroll
    for (int i = 0; i < 4; ++i) bb1[c][i] = b1[16*(2*w + c) + 4*g + i];
#pragma unroll
  for (int i = 0; i < 4; ++i) bb2v[i] = b2[16*w + 4*g + i];

  // ---- per-lane fp32 state as f32x2 pairs: batch row m (if valid), cols ccol..+3 ----
  const int ccol = 16*w + 4*g;
  f32x2 y[2], k1[2], k2[2], k3[2], yn[2];
  if (rowok && ccol < 64) {
    const float4 v = *(const float4*)&x0[(row0 + m)*64 + ccol];
    y[0][0]=v.x; y[0][1]=v.y; y[1][0]=v.z; y[1][1]=v.w;
  } else {
    y[0] = (f32x2){0.f,0.f}; y[1] = (f32x2){0.f,0.f};
  }
  yn[0] = y[0]; yn[1] = y[1];
  if (rowok && ccol < 64) {   // sol[0] = x0
    float4 v; v.x=y[0][0]; v.y=y[0][1]; v.z=y[1][0]; v.w=y[1][1];
    *(float4*)&out[(row0 + m)*64 + ccol] = v;
  }
  *(f16x4*)&Yh[m][ccol] = cvt4(yn[0], yn[1]);
  __syncthreads();

  for (int step = 0; step < T_STEPS; ++step) {
    const float dt = vsub(tarr[step+1], tarr[step]);
    const f32x2 dt2      = { dt, dt };
    const f32x2 third2   = { dt*(1.f/3.f), dt*(1.f/3.f) };
    const f32x2 mthird2  = { -1.f/3.f, -1.f/3.f };
    const f32x2 three2   = { 3.f, 3.f };
    const f32x2 dt8      = { dt*0.125f, dt*0.125f };

#pragma unroll
    for (int stage = 0; stage < 4; ++stage) {
      // layer 1 (swapped): lane holds H[16(2w+c)+4g+i][row m]
      f32x4 acc0 = bb1[0], acc1 = bb1[1];
#pragma unroll
      for (int kk = 0; kk < 4; ++kk) {
        f16x8 a = ld_frag(&Yh[m][kk*32 + 8*g]);
        acc0 = __builtin_amdgcn_mfma_f32_16x16x32_f16(wB1[0][kk], a, acc0, 0,0,0);
        acc1 = __builtin_amdgcn_mfma_f32_16x16x32_f16(wB1[1][kk], a, acc1, 0,0,0);
      }
      {
        f32x2 t00 = tanh2((f32x2){acc0[0], acc0[1]});
        f32x2 t01 = tanh2((f32x2){acc0[2], acc0[3]});
        f32x2 t10 = tanh2((f32x2){acc1[0], acc1[1]});
        f32x2 t11 = tanh2((f32x2){acc1[2], acc1[3]});
        *(f16x4*)&Hh[m][16*(2*w+0) + 4*g] = cvt4(t00, t01);
        *(f16x4*)&Hh[m][16*(2*w+1) + 4*g] = cvt4(t10, t11);
      }
      __syncthreads();

      // layer 2 (swapped): lane holds K[16w+4g+i][row m]
      f32x4 accA = bb2v;
      f32x4 accB = { 0.f, 0.f, 0.f, 0.f };
#pragma unroll
      for (int kk = 0; kk < 4; ++kk) {
        f16x8 aA = ld_frag(&Hh[m][kk*32 + 8*g]);
        f16x8 aB = ld_frag(&Hh[m][(kk+4)*32 + 8*g]);
        accA = __builtin_amdgcn_mfma_f32_16x16x32_f16(wB2[kk],   aA, accA, 0,0,0);
        accB = __builtin_amdgcn_mfma_f32_16x16x32_f16(wB2[kk+4], aB, accB, 0,0,0);
      }
      f32x2 ks[2];
      ks[0] = (f32x2){accA[0],accA[1]} + (f32x2){accB[0],accB[1]};
      ks[1] = (f32x2){accA[2],accA[3]} + (f32x2){accB[2],accB[3]};

      // RK4 (3/8 rule) bookkeeping, packed via native vector ops
      if (stage == 0) {
#pragma unroll
        for (int p = 0; p < 2; ++p) { k1[p] = ks[p]; yn[p] = vfma2(k1[p], third2, y[p]); }
      } else if (stage == 1) {
#pragma unroll
        for (int p = 0; p < 2; ++p) {
          k2[p] = ks[p];
          f32x2 a = vfma2(k1[p], mthird2, k2[p]);    // k2 - k1/3
          yn[p] = vfma2(a, dt2, y[p]);
        }
      } else if (stage == 2) {
#pragma unroll
        for (int p = 0; p < 2; ++p) {
          k3[p] = ks[p];
          f32x2 b = (k1[p] - k2[p]) + k3[p];
          yn[p] = vfma2(b, dt2, y[p]);
        }
      } else {
#pragma unroll
        for (int p = 0; p < 2; ++p) {
          f32x2 s1 = k2[p] + k3[p];
          f32x2 s2 = vfma2(s1, three2, k1[p]);       // k1 + 3(k2+k3)
          f32x2 s3 = s2 + ks[p];                     // + k4
          y[p] = vfma2(s3, dt8, y[p]);
          yn[p] = y[p];
        }
        if (rowok && ccol < 64) {
          float4 v; v.x=y[0][0]; v.y=y[0][1]; v.z=y[1][0]; v.w=y[1][1];
          *(float4*)&out[(size_t)(step+1)*OUTSTRIDE + (row0 + m)*64 + ccol] = v;
        }
      }
      // next stage input -> LDS (packed b64)
      *(f16x4*)&Yh[m][ccol] = cvt4(yn[0], yn[1]);
      __syncthreads();
    }
  }
}

extern "C" void kernel_launch(void* const* d_in, const int* in_sizes, int n_in,
                              void* d_out, int out_size, void* d_ws, size_t ws_size,
                              hipStream_t stream) {
  const float* x0 = (const float*)d_in[0];
  const float* t  = (const float*)d_in[1];
  const float* W1 = (const float*)d_in[2];
  const float* b1 = (const float*)d_in[3];
  const float* W2 = (const float*)d_in[4];
  const float* b2 = (const float*)d_in[5];
  float* out = (float*)d_out;
  hipLaunchKernelGGL(node_rk4_kernel, dim3(4096/BM), dim3(512), 0, stream,
                     x0, t, W1, b1, W2, b2, out);
}

// Round 14
// 156.638 us; speedup vs baseline: 1.6623x; 1.6623x over previous
//
#include <hip/hip_runtime.h>

typedef __attribute__((ext_vector_type(8))) _Float16 f16x8;
typedef __attribute__((ext_vector_type(4))) _Float16 f16x4;
typedef __attribute__((ext_vector_type(2))) _Float16 f16x2;
typedef __attribute__((ext_vector_type(4))) float f32x4;
typedef __attribute__((ext_vector_type(2))) float f32x2;

#define T_STEPS 49
#define BM 16
#define OUTSTRIDE (4096*64)
#define YSTR 140   // f16/row: 280B = 70 dw == 6 mod 8 -> all access families <=2-way banks
#define HSTR 268   // f16/row: 536B = 134 dw == 6 mod 8 -> same

__device__ __forceinline__ f16x8 ld_frag(const _Float16* p) {
  f16x4 a = *(const f16x4*)p;        // rows 8B-aligned
  f16x4 b = *(const f16x4*)(p + 4);
  return __builtin_shufflevector(a, b, 0,1,2,3,4,5,6,7);
}
// Backend bug workaround: v-op with two SGPR sources violates constant-bus rule.
__device__ __forceinline__ float vsub(float a, float b) {
  float r;
  asm("v_sub_f32 %0, %1, %2" : "=v"(r) : "v"(a), "v"(b));
  return r;
}
// Packed f32 via native vector ops (compiler-encoded VOP3P; R10/R11: never
// hand-write VOP3P asm — modifier defaults corrupt the hi half).
__device__ __forceinline__ f32x2 vfma2(f32x2 a, f32x2 b, f32x2 c) {
  return __builtin_elementwise_fma(a, b, c);
}
__device__ __forceinline__ f32x2 tanh2(f32x2 x) {
  const f32x2 c2  = { 2.885390081777927f, 2.885390081777927f };
  const f32x2 one = { 1.f, 1.f };
  const f32x2 m2  = { -2.f, -2.f };
  f32x2 t = x * c2;
  f32x2 e;
  e[0] = __builtin_amdgcn_exp2f(t[0]);
  e[1] = __builtin_amdgcn_exp2f(t[1]);
  f32x2 ep1 = e + one;
  f32x2 r;
  r[0] = __builtin_amdgcn_rcpf(ep1[0]);
  r[1] = __builtin_amdgcn_rcpf(ep1[1]);
  return vfma2(r, m2, one);           // 1 - 2/(e^{2x}+1)
}
__device__ __forceinline__ f16x4 cvt4(f32x2 a, f32x2 b) {
  f16x2 h0 = __builtin_bit_cast(f16x2, __builtin_amdgcn_cvt_pkrtz(a[0], a[1]));
  f16x2 h1 = __builtin_bit_cast(f16x2, __builtin_amdgcn_cvt_pkrtz(b[0], b[1]));
  return __builtin_shufflevector(h0, h1, 0,1,2,3);
}

// WAVE-SPECIALIZED: 8 waves, BM=16, grid 256 = 1 WG/CU.
// Waves 4-7 ("B"): layer 1 only. Wave wb owns H cols [64wb,64wb+64) (4 tiles);
//   reads Y (4KB), writes its H cols. Waves 0-3 ("A"): layer 2 + RK4 + state.
//   Wave w owns K cols [32w,32w+32) (2 tiles); reads H (8KB), writes its Y cols.
// LDS bytes/eval: 104KB (symmetric R12) -> 60KB: Y-r 16 + H-r 32 + writes 12.
// The LDS pipe (~88 B/cyc measured) was the R12/R13 floor; MFMA count unchanged.
// Weight frags share ONE 16-frag register array (W1 for B, W2 for A).
__global__ __launch_bounds__(512)
void node_rk4_kernel(const float* __restrict__ x0, const float* __restrict__ tarr,
                     const float* __restrict__ W1, const float* __restrict__ b1,
                     const float* __restrict__ W2, const float* __restrict__ b2,
                     float* __restrict__ out)
{
  __shared__ __align__(16) _Float16 Yh[16][YSTR];
  __shared__ __align__(16) _Float16 Hh[16][HSTR];

  const int tid  = threadIdx.x;
  const int w    = tid >> 6;        // wave 0..7
  const int lane = tid & 63;
  const int m    = lane & 15;       // batch row (output col of swapped MFMA)
  const int g    = lane >> 4;       // 0..3
  const int row0 = (int)blockIdx.x * BM;
  const bool isA = (w < 4);
  const int wb   = w - 4;           // B-wave index 0..3 (valid when !isA)

  // ---- role-specific weight fragments, SHARED register array (16 frags) ----
  // intra-chunk K mapping k = kk*32+8g+j, same wiring both operands -> cancels.
  f16x8 wB[16];
  f32x4 bias[4];
  if (isA) {
    // W2 frags: wB[t*8+kk] holds W2[kk*32+8g+j][32w+16t+m]
#pragma unroll
    for (int t = 0; t < 2; ++t)
#pragma unroll
      for (int kk = 0; kk < 8; ++kk) {
        f16x8 v;
#pragma unroll
        for (int j = 0; j < 8; ++j)
          v[j] = (_Float16)W2[(kk*32 + 8*g + j)*128 + (32*w + 16*t + m)];
        wB[t*8 + kk] = v;
      }
#pragma unroll
    for (int t = 0; t < 2; ++t)
#pragma unroll
      for (int i = 0; i < 4; ++i) bias[t][i] = b2[32*w + 16*t + 4*g + i];
  } else {
    // W1 frags: wB[c*4+kk] holds W1[kk*32+8g+j][64wb+16c+m]
#pragma unroll
    for (int c = 0; c < 4; ++c)
#pragma unroll
      for (int kk = 0; kk < 4; ++kk) {
        f16x8 v;
#pragma unroll
        for (int j = 0; j < 8; ++j)
          v[j] = (_Float16)W1[(kk*32 + 8*g + j)*256 + (64*wb + 16*c + m)];
        wB[c*4 + kk] = v;
      }
#pragma unroll
    for (int c = 0; c < 4; ++c)
#pragma unroll
      for (int i = 0; i < 4; ++i) bias[c][i] = b1[64*wb + 16*c + 4*g + i];
  }

  // ---- A-wave state: row m, y cols 32w+16t+4g+{0..3}, t=0,1 ----
  f32x2 y[2][2], k1[2][2], k2[2][2], k3[2][2], yn[2][2];
#pragma unroll
  for (int t = 0; t < 2; ++t)
#pragma unroll
    for (int p = 0; p < 2; ++p) { y[t][p] = (f32x2){0.f,0.f}; yn[t][p] = y[t][p]; }
  if (isA) {
    if (w < 2) {   // cols 32w..32w+31 all < 64
#pragma unroll
      for (int t = 0; t < 2; ++t) {
        const float4 v = *(const float4*)&x0[(row0 + m)*64 + 32*w + 16*t + 4*g];
        y[t][0] = (f32x2){v.x, v.y}; y[t][1] = (f32x2){v.z, v.w};
        yn[t][0] = y[t][0]; yn[t][1] = y[t][1];
        *(float4*)&out[(row0 + m)*64 + 32*w + 16*t + 4*g] = v;   // sol[0] = x0
      }
    }
#pragma unroll
    for (int t = 0; t < 2; ++t)
      *(f16x4*)&Yh[m][32*w + 16*t + 4*g] = cvt4(yn[t][0], yn[t][1]);
  }
  __syncthreads();

  for (int step = 0; step < T_STEPS; ++step) {
    const float dt = vsub(tarr[step+1], tarr[step]);
    const f32x2 dt2      = { dt, dt };
    const f32x2 third2   = { dt*(1.f/3.f), dt*(1.f/3.f) };
    const f32x2 mthird2  = { -1.f/3.f, -1.f/3.f };
    const f32x2 three2   = { 3.f, 3.f };
    const f32x2 dt8      = { dt*0.125f, dt*0.125f };

#pragma unroll
    for (int stage = 0; stage < 4; ++stage) {
      // ---- phase 1 (waves 4-7): H = tanh(Y @ W1 + b1), 4 col-tiles ----
      if (!isA) {
        f32x4 acc[4];
#pragma unroll
        for (int c = 0; c < 4; ++c) acc[c] = bias[c];
#pragma unroll
        for (int kk = 0; kk < 4; ++kk) {
          f16x8 a = ld_frag(&Yh[m][kk*32 + 8*g]);
#pragma unroll
          for (int c = 0; c < 4; ++c)
            acc[c] = __builtin_amdgcn_mfma_f32_16x16x32_f16(wB[c*4 + kk], a, acc[c], 0,0,0);
        }
#pragma unroll
        for (int c = 0; c < 4; ++c) {
          f32x2 t0 = tanh2((f32x2){acc[c][0], acc[c][1]});
          f32x2 t1 = tanh2((f32x2){acc[c][2], acc[c][3]});
          *(f16x4*)&Hh[m][64*wb + 16*c + 4*g] = cvt4(t0, t1);
        }
      }
      __syncthreads();

      // ---- phase 2 (waves 0-3): K = H @ W2 + b2, RK4, Y(next), out ----
      if (isA) {
        f32x4 acc[2];
#pragma unroll
        for (int t = 0; t < 2; ++t) acc[t] = bias[t];
#pragma unroll
        for (int kk = 0; kk < 8; ++kk) {
          f16x8 a = ld_frag(&Hh[m][kk*32 + 8*g]);
#pragma unroll
          for (int t = 0; t < 2; ++t)
            acc[t] = __builtin_amdgcn_mfma_f32_16x16x32_f16(wB[t*8 + kk], a, acc[t], 0,0,0);
        }
        f32x2 ks[2][2];
#pragma unroll
        for (int t = 0; t < 2; ++t) {
          ks[t][0] = (f32x2){acc[t][0], acc[t][1]};
          ks[t][1] = (f32x2){acc[t][2], acc[t][3]};
        }
        if (stage == 0) {
#pragma unroll
          for (int t = 0; t < 2; ++t)
#pragma unroll
            for (int p = 0; p < 2; ++p) { k1[t][p] = ks[t][p]; yn[t][p] = vfma2(k1[t][p], third2, y[t][p]); }
        } else if (stage == 1) {
#pragma unroll
          for (int t = 0; t < 2; ++t)
#pragma unroll
            for (int p = 0; p < 2; ++p) {
              k2[t][p] = ks[t][p];
              f32x2 a = vfma2(k1[t][p], mthird2, k2[t][p]);   // k2 - k1/3
              yn[t][p] = vfma2(a, dt2, y[t][p]);
            }
        } else if (stage == 2) {
#pragma unroll
          for (int t = 0; t < 2; ++t)
#pragma unroll
            for (int p = 0; p < 2; ++p) {
              k3[t][p] = ks[t][p];
              f32x2 b = (k1[t][p] - k2[t][p]) + k3[t][p];
              yn[t][p] = vfma2(b, dt2, y[t][p]);
            }
        } else {
#pragma unroll
          for (int t = 0; t < 2; ++t)
#pragma unroll
            for (int p = 0; p < 2; ++p) {
              f32x2 s1 = k2[t][p] + k3[t][p];
              f32x2 s2 = vfma2(s1, three2, k1[t][p]);         // k1 + 3(k2+k3)
              f32x2 s3 = s2 + ks[t][p];                       // + k4
              y[t][p] = vfma2(s3, dt8, y[t][p]);
              yn[t][p] = y[t][p];
            }
          if (w < 2) {
#pragma unroll
            for (int t = 0; t < 2; ++t) {
              float4 v; v.x=y[t][0][0]; v.y=y[t][0][1]; v.z=y[t][1][0]; v.w=y[t][1][1];
              *(float4*)&out[(size_t)(step+1)*OUTSTRIDE + (row0 + m)*64 + 32*w + 16*t + 4*g] = v;
            }
          }
        }
        // next stage input -> LDS (2 packed b64)
#pragma unroll
        for (int t = 0; t < 2; ++t)
          *(f16x4*)&Yh[m][32*w + 16*t + 4*g] = cvt4(yn[t][0], yn[t][1]);
      }
      __syncthreads();
    }
  }
}

extern "C" void kernel_launch(void* const* d_in, const int* in_sizes, int n_in,
                              void* d_out, int out_size, void* d_ws, size_t ws_size,
                              hipStream_t stream) {
  const float* x0 = (const float*)d_in[0];
  const float* t  = (const float*)d_in[1];
  const float* W1 = (const float*)d_in[2];
  const float* b1 = (const float*)d_in[3];
  const float* W2 = (const float*)d_in[4];
  const float* b2 = (const float*)d_in[5];
  float* out = (float*)d_out;
  hipLaunchKernelGGL(node_rk4_kernel, dim3(4096/BM), dim3(512), 0, stream,
                     x0, t, W1, b1, W2, b2, out);
}

// Round 15
// 150.396 us; speedup vs baseline: 1.7313x; 1.0415x over previous
//
#include <hip/hip_runtime.h>

typedef __attribute__((ext_vector_type(8))) _Float16 f16x8;
typedef __attribute__((ext_vector_type(4))) _Float16 f16x4;
typedef __attribute__((ext_vector_type(2))) _Float16 f16x2;
typedef __attribute__((ext_vector_type(4))) float f32x4;

#define T_STEPS 49
#define BM 16
#define OUTSTRIDE (4096*64)
#define YSTR 136   // f16/row: 272B = 17x16 -> rows 16B-aligned (ds_read_b128);
#define HSTR 264   // b64 writes spread 2-way (free); b128 reads uniform 8/bank.

// Backend bug workaround: v-op with two SGPR sources violates constant-bus rule.
__device__ __forceinline__ float vsub(float a, float b) {
  float r;
  asm("v_sub_f32 %0, %1, %2" : "=v"(r) : "v"(a), "v"(b));
  return r;
}
// 4-wide helpers: native vector ops -> ISel emits VOP3P pairs (never hand-write
// VOP3P asm: R10/R11 modifier corruption).
__device__ __forceinline__ f32x4 vfma4(f32x4 a, f32x4 b, f32x4 c) {
  return __builtin_elementwise_fma(a, b, c);
}
__device__ __forceinline__ f32x4 tanh4(f32x4 x) {
  const f32x4 c2  = { 2.885390081777927f, 2.885390081777927f, 2.885390081777927f, 2.885390081777927f };
  const f32x4 one = { 1.f, 1.f, 1.f, 1.f };
  const f32x4 m2  = { -2.f, -2.f, -2.f, -2.f };
  f32x4 t = x * c2;
  f32x4 e;
  e[0] = __builtin_amdgcn_exp2f(t[0]);
  e[1] = __builtin_amdgcn_exp2f(t[1]);
  e[2] = __builtin_amdgcn_exp2f(t[2]);
  e[3] = __builtin_amdgcn_exp2f(t[3]);
  f32x4 ep1 = e + one;
  f32x4 r;
  r[0] = __builtin_amdgcn_rcpf(ep1[0]);
  r[1] = __builtin_amdgcn_rcpf(ep1[1]);
  r[2] = __builtin_amdgcn_rcpf(ep1[2]);
  r[3] = __builtin_amdgcn_rcpf(ep1[3]);
  return vfma4(r, m2, one);           // 1 - 2/(e^{2x}+1)
}
__device__ __forceinline__ f16x4 cvt4(f32x4 a) {
  f16x2 h0 = __builtin_bit_cast(f16x2, __builtin_amdgcn_cvt_pkrtz(a[0], a[1]));
  f16x2 h1 = __builtin_bit_cast(f16x2, __builtin_amdgcn_cvt_pkrtz(a[2], a[3]));
  return __builtin_shufflevector(h0, h1, 0,1,2,3);
}

// 8-wave WG, BM=16 rows, grid 256 = 1 WG/CU. R12 structure (swapped-operand
// MFMAs, packed b64 LDS writes, symmetric waves) with: single-b128 LDS frags
// (16B-aligned strides), f32x4-native RK4/tanh (no pair-extraction movs), and
// tanh0 source-interleaved into MFMA chain1 for in-wave VALU||MFMA overlap.
__global__ __launch_bounds__(512)
void node_rk4_kernel(const float* __restrict__ x0, const float* __restrict__ tarr,
                     const float* __restrict__ W1, const float* __restrict__ b1,
                     const float* __restrict__ W2, const float* __restrict__ b2,
                     float* __restrict__ out)
{
  __shared__ __align__(16) _Float16 Yh[16][YSTR];
  __shared__ __align__(16) _Float16 Hh[16][HSTR];

  const int tid  = threadIdx.x;
  const int w    = tid >> 6;        // wave 0..7
  const int lane = tid & 63;
  const int m    = lane & 15;       // batch row owned by this lane (output side)
  const int g    = lane >> 4;       // 0..3
  const int row0 = (int)blockIdx.x * BM;

  // ---- weight fragments in registers ----
  // intra-chunk K mapping: k = kk*32 + 8*g + j (same wiring both operands -> cancels)
  f16x8 wB1[2][4], wB2[8];
#pragma unroll
  for (int c = 0; c < 2; ++c)
#pragma unroll
    for (int kk = 0; kk < 4; ++kk) {
      f16x8 v;
#pragma unroll
      for (int j = 0; j < 8; ++j)
        v[j] = (_Float16)W1[(kk*32 + 8*g + j)*256 + (32*w + 16*c + m)];
      wB1[c][kk] = v;
    }
#pragma unroll
  for (int kk = 0; kk < 8; ++kk) {
    f16x8 v;
#pragma unroll
    for (int j = 0; j < 8; ++j)
      v[j] = (_Float16)W2[(kk*32 + 8*g + j)*128 + (16*w + m)];
    wB2[kk] = v;
  }
  // biases: transposed D-frag -> per-reg bias (row index 4g+i of the tile)
  f32x4 bb1[2], bb2v;
#pragma unroll
  for (int c = 0; c < 2; ++c)
#pragma unroll
    for (int i = 0; i < 4; ++i) bb1[c][i] = b1[16*(2*w + c) + 4*g + i];
#pragma unroll
  for (int i = 0; i < 4; ++i) bb2v[i] = b2[16*w + 4*g + i];

  // ---- per-lane fp32 state: batch row m, y cols ccol..ccol+3 ----
  const int ccol = 16*w + 4*g;
  const _Float16* __restrict__ Yrow = &Yh[m][0];
  const _Float16* __restrict__ Hrow = &Hh[m][0];
  f32x4 y, k1v, k2v, k3v, yn;
  if (ccol < 64) {
    y = *(const f32x4*)&x0[(row0 + m)*64 + ccol];
  } else {
    y = (f32x4){0.f,0.f,0.f,0.f};
  }
  yn = y;
  if (ccol < 64) {   // sol[0] = x0
    *(f32x4*)&out[(row0 + m)*64 + ccol] = y;
  }
  *(f16x4*)&Yh[m][ccol] = cvt4(yn);
  __syncthreads();

  for (int step = 0; step < T_STEPS; ++step) {
    const float dt = vsub(tarr[step+1], tarr[step]);
    const f32x4 dt4     = { dt, dt, dt, dt };
    const f32x4 third4  = { dt*(1.f/3.f), dt*(1.f/3.f), dt*(1.f/3.f), dt*(1.f/3.f) };
    const f32x4 mthird4 = { -1.f/3.f, -1.f/3.f, -1.f/3.f, -1.f/3.f };
    const f32x4 three4  = { 3.f, 3.f, 3.f, 3.f };
    const f32x4 dt8     = { dt*0.125f, dt*0.125f, dt*0.125f, dt*0.125f };

#pragma unroll
    for (int stage = 0; stage < 4; ++stage) {
      // ---- layer 1 (swapped): lane holds H[m][16(2w+c)+4g+i] ----
      f16x8 a0 = *(const f16x8*)(Yrow + 0*32 + 8*g);   // ds_read_b128 each
      f16x8 a1 = *(const f16x8*)(Yrow + 1*32 + 8*g);
      f16x8 a2 = *(const f16x8*)(Yrow + 2*32 + 8*g);
      f16x8 a3 = *(const f16x8*)(Yrow + 3*32 + 8*g);
      f32x4 acc0 = bb1[0];
      acc0 = __builtin_amdgcn_mfma_f32_16x16x32_f16(wB1[0][0], a0, acc0, 0,0,0);
      acc0 = __builtin_amdgcn_mfma_f32_16x16x32_f16(wB1[0][1], a1, acc0, 0,0,0);
      acc0 = __builtin_amdgcn_mfma_f32_16x16x32_f16(wB1[0][2], a2, acc0, 0,0,0);
      acc0 = __builtin_amdgcn_mfma_f32_16x16x32_f16(wB1[0][3], a3, acc0, 0,0,0);
      f32x4 acc1 = bb1[1];
      acc1 = __builtin_amdgcn_mfma_f32_16x16x32_f16(wB1[1][0], a0, acc1, 0,0,0);
      acc1 = __builtin_amdgcn_mfma_f32_16x16x32_f16(wB1[1][1], a1, acc1, 0,0,0);
      // tanh(acc0) on the VALU pipe while chain1 finishes on the matrix pipe
      f32x4 t0 = tanh4(acc0);
      acc1 = __builtin_amdgcn_mfma_f32_16x16x32_f16(wB1[1][2], a2, acc1, 0,0,0);
      *(f16x4*)&Hh[m][16*(2*w+0) + 4*g] = cvt4(t0);
      acc1 = __builtin_amdgcn_mfma_f32_16x16x32_f16(wB1[1][3], a3, acc1, 0,0,0);
      f32x4 t1 = tanh4(acc1);
      *(f16x4*)&Hh[m][16*(2*w+1) + 4*g] = cvt4(t1);
      __syncthreads();

      // ---- layer 2 (swapped): lane holds K[m][16w+4g+i] ----
      f16x8 h0 = *(const f16x8*)(Hrow + 0*32 + 8*g);
      f16x8 h1 = *(const f16x8*)(Hrow + 1*32 + 8*g);
      f16x8 h2 = *(const f16x8*)(Hrow + 2*32 + 8*g);
      f16x8 h3 = *(const f16x8*)(Hrow + 3*32 + 8*g);
      f16x8 h4 = *(const f16x8*)(Hrow + 4*32 + 8*g);
      f16x8 h5 = *(const f16x8*)(Hrow + 5*32 + 8*g);
      f16x8 h6 = *(const f16x8*)(Hrow + 6*32 + 8*g);
      f16x8 h7 = *(const f16x8*)(Hrow + 7*32 + 8*g);
      f32x4 accA = bb2v;
      f32x4 accB = { 0.f, 0.f, 0.f, 0.f };
      accA = __builtin_amdgcn_mfma_f32_16x16x32_f16(wB2[0], h0, accA, 0,0,0);
      accB = __builtin_amdgcn_mfma_f32_16x16x32_f16(wB2[4], h4, accB, 0,0,0);
      accA = __builtin_amdgcn_mfma_f32_16x16x32_f16(wB2[1], h1, accA, 0,0,0);
      accB = __builtin_amdgcn_mfma_f32_16x16x32_f16(wB2[5], h5, accB, 0,0,0);
      accA = __builtin_amdgcn_mfma_f32_16x16x32_f16(wB2[2], h2, accA, 0,0,0);
      accB = __builtin_amdgcn_mfma_f32_16x16x32_f16(wB2[6], h6, accB, 0,0,0);
      accA = __builtin_amdgcn_mfma_f32_16x16x32_f16(wB2[3], h3, accA, 0,0,0);
      accB = __builtin_amdgcn_mfma_f32_16x16x32_f16(wB2[7], h7, accB, 0,0,0);
      f32x4 ks = accA + accB;

      // ---- RK4 (3/8 rule) bookkeeping, f32x4-native ----
      if (stage == 0) {
        k1v = ks; yn = vfma4(k1v, third4, y);
      } else if (stage == 1) {
        k2v = ks;
        yn = vfma4(vfma4(k1v, mthird4, k2v), dt4, y);   // y + dt*(k2 - k1/3)
      } else if (stage == 2) {
        k3v = ks;
        yn = vfma4((k1v - k2v) + k3v, dt4, y);
      } else {
        f32x4 s = vfma4(k2v + k3v, three4, k1v) + ks;   // k1 + 3(k2+k3) + k4
        y = vfma4(s, dt8, y);
        yn = y;
        if (ccol < 64)
          *(f32x4*)&out[(size_t)(step+1)*OUTSTRIDE + (row0 + m)*64 + ccol] = y;
      }
      // next stage input -> LDS (packed b64)
      *(f16x4*)&Yh[m][ccol] = cvt4(yn);
      __syncthreads();
    }
  }
}

extern "C" void kernel_launch(void* const* d_in, const int* in_sizes, int n_in,
                              void* d_out, int out_size, void* d_ws, size_t ws_size,
                              hipStream_t stream) {
  const float* x0 = (const float*)d_in[0];
  const float* t  = (const float*)d_in[1];
  const float* W1 = (const float*)d_in[2];
  const float* b1 = (const float*)d_in[3];
  const float* W2 = (const float*)d_in[4];
  const float* b2 = (const float*)d_in[5];
  float* out = (float*)d_out;
  hipLaunchKernelGGL(node_rk4_kernel, dim3(4096/BM), dim3(512), 0, stream,
                     x0, t, W1, b1, W2, b2, out);
}